// Round 2
// 119.534 us; speedup vs baseline: 1.0402x; 1.0402x over previous
//
#include <hip/hip_runtime.h>

#define NATOMS 8192
#define DD 128     // embedding dim
#define HH 256     // hidden dim
#define TI 4       // atoms per block in aggregation (verbatim from passing kernel)
#define MAXE 128   // max edges per atom (mean ~20, Poisson; 128 is >>6 sigma)
#define MB 16      // nodes per block in MLP
#define MTH 512    // k_mlp threads (8 waves) -> 512 blocks x 8 = 16 waves/CU

// out is poisoned 0xAA before every launch; zero it for the atomic reduction.
__global__ void k_zero(float* out) { if (threadIdx.x == 0) out[0] = 0.0f; }

// One block handles TI atoms: O(N) distance sweep, compact valid edges
// (w = exp(-d), row = type[j]*DD) into LDS lists, then sparse-aggregate
// agg[i][:] = sum_e w_e * emb[row_e][:].   [VERBATIM from 124us passing kernel]
__global__ __launch_bounds__(256) void k_agg(const float* __restrict__ pos,
                                             const int* __restrict__ types,
                                             const float* __restrict__ emb,
                                             float* __restrict__ agg) {
  __shared__ float sw[TI][MAXE];
  __shared__ int   srow[TI][MAXE];
  __shared__ int   scnt[TI];
  const int tid = threadIdx.x;
  const int i0 = blockIdx.x * TI;
  if (tid < TI) scnt[tid] = 0;

  float pix[TI], piy[TI], piz[TI];
#pragma unroll
  for (int m = 0; m < TI; ++m) {   // uniform addresses -> scalar loads
    pix[m] = 10.0f * pos[(i0 + m) * 3 + 0];
    piy[m] = 10.0f * pos[(i0 + m) * 3 + 1];
    piz[m] = 10.0f * pos[(i0 + m) * 3 + 2];
  }
  __syncthreads();

  for (int j = tid; j < NATOMS; j += 256) {
    float pjx = 10.0f * pos[j * 3 + 0];
    float pjy = 10.0f * pos[j * 3 + 1];
    float pjz = 10.0f * pos[j * 3 + 2];
#pragma unroll
    for (int m = 0; m < TI; ++m) {
      float dx = pix[m] - pjx, dy = piy[m] - pjy, dz = piz[m] - pjz;
      float d2 = dx * dx;
      d2 = fmaf(dy, dy, d2);
      d2 = fmaf(dz, dz, d2);
      // ref mask: d2 > 1e-12 && sqrt(d2) <= 5  <=>  1e-12 < d2 <= 25 (fp32-exact)
      if (d2 > 1e-12f && d2 <= 25.0f) {
        float w = __expf(-sqrtf(d2));
        int e = atomicAdd(&scnt[m], 1);
        if (e < MAXE) {
          sw[m][e] = w;
          srow[m][e] = types[j] * DD;
        }
      }
    }
  }
  __syncthreads();

  // 256 threads = 2 groups of 128 dims; group g handles atoms {g, g+2}
  const int d = tid & (DD - 1);
  const int g = tid >> 7;
#pragma unroll
  for (int mm = 0; mm < TI; mm += 2) {
    int m = g + mm;
    int nc = min(scnt[m], MAXE);
    float a = 0.0f;
    for (int e = 0; e < nc; ++e)
      a = fmaf(sw[m][e], emb[srow[m][e] + d], a);
    agg[(size_t)(i0 + m) * DD + d] = a;
  }
}

// MLP: e_node = relu([h,agg] @ W1) @ w2, summed into out (kcal/mol).
// Block = 16 nodes, 512 threads (was 256): thread (tx=tid&127, ty=tid>>7)
// computes hidden units {tx, tx+128} for 4 nodes (was 8). Same per-(node,
// hidden) FMA chains; 2x the waves (16/CU) to hide W1 load latency.
__global__ __launch_bounds__(MTH) void k_mlp(const int* __restrict__ types,
                                             const float* __restrict__ emb,
                                             const float* __restrict__ agg,
                                             const float* __restrict__ W1,
                                             const float* __restrict__ w2,
                                             float* __restrict__ out) {
  __shared__ float sf[2 * DD][MB];  // feat transposed [j][m], 16 KB
  __shared__ float sred[MTH / 64];
  const int tid = threadIdx.x;
  const int n0 = blockIdx.x * MB;

  // stage feat = concat(h, agg): conflict-free, consecutive idx -> consecutive LDS
  for (int idx = tid; idx < MB * 2 * DD; idx += MTH) {
    int j = idx >> 4;        // 0..255
    int m = idx & (MB - 1);  // 0..15
    float v;
    if (j < DD) v = emb[types[n0 + m] * DD + j];
    else        v = agg[(size_t)(n0 + m) * DD + (j - DD)];
    sf[j][m] = v;
  }
  __syncthreads();

  const int tx = tid & 127;
  const int ty = tid >> 7;   // 0..3 -> nodes ty*4 .. ty*4+3
  float acc0[4], acc1[4];
#pragma unroll
  for (int m = 0; m < 4; ++m) { acc0[m] = 0.0f; acc1[m] = 0.0f; }

  const float* fbase = &sf[0][ty * 4];
#pragma unroll 4
  for (int j = 0; j < 2 * DD; ++j) {
    float w0 = W1[j * HH + tx];          // coalesced, L1/L2-hot
    float w1 = W1[j * HH + tx + 128];
    float f[4];
    *(float4*)&f[0] = *(const float4*)(fbase + j * MB);  // LDS broadcast
#pragma unroll
    for (int m = 0; m < 4; ++m) {
      acc0[m] = fmaf(f[m], w0, acc0[m]);
      acc1[m] = fmaf(f[m], w1, acc1[m]);
    }
  }

  float s0 = 0.0f, s1 = 0.0f;
#pragma unroll
  for (int m = 0; m < 4; ++m) {
    s0 += fmaxf(acc0[m], 0.0f);
    s1 += fmaxf(acc1[m], 0.0f);
  }
  float p = s0 * w2[tx] + s1 * w2[tx + 128];
#pragma unroll
  for (int off = 32; off; off >>= 1) p += __shfl_down(p, off);  // wave64 reduce
  if ((tid & 63) == 0) sred[tid >> 6] = p;
  __syncthreads();
  if (tid == 0) {
    float t = 0.0f;
#pragma unroll
    for (int q = 0; q < MTH / 64; ++q) t += sred[q];
    atomicAdd(out, t * 0.2390057361376673f);
  }
}

extern "C" void kernel_launch(void* const* d_in, const int* in_sizes, int n_in,
                              void* d_out, int out_size, void* d_ws, size_t ws_size,
                              hipStream_t stream) {
  const float* pos = (const float*)d_in[0];
  const int*   typ = (const int*)d_in[1];
  const float* emb = (const float*)d_in[2];
  const float* W1  = (const float*)d_in[3];
  const float* w2  = (const float*)d_in[4];
  float* out = (float*)d_out;
  float* agg = (float*)d_ws;  // 8192*128 floats = 4 MB scratch

  hipLaunchKernelGGL(k_zero, dim3(1), dim3(64), 0, stream, out);
  hipLaunchKernelGGL(k_agg, dim3(NATOMS / TI), dim3(256), 0, stream,
                     pos, typ, emb, agg);
  hipLaunchKernelGGL(k_mlp, dim3(NATOMS / MB), dim3(MTH), 0, stream,
                     typ, emb, agg, W1, w2, out);
}

// Round 3
// 116.917 us; speedup vs baseline: 1.0635x; 1.0224x over previous
//
#include <hip/hip_runtime.h>

#define NATOMS 8192
#define DD 128     // embedding dim
#define HH 256     // hidden dim
#define TI 4       // atoms per block in aggregation (verbatim from passing kernel)
#define MAXE 128   // max edges per atom (mean ~20, Poisson; 128 is >>6 sigma)
#define MB 32      // nodes per block in MLP
#define MTH 512    // k_mlp threads (8 waves); grid=256 -> 1 block/CU

// out is poisoned 0xAA before every launch; zero it for the atomic reduction.
__global__ void k_zero(float* out) { if (threadIdx.x == 0) out[0] = 0.0f; }

// One block handles TI atoms: O(N) distance sweep, compact valid edges
// (w = exp(-d), row = type[j]*DD) into LDS lists, then sparse-aggregate
// agg[i][:] = sum_e w_e * emb[row_e][:].   [VERBATIM from passing kernel]
__global__ __launch_bounds__(256) void k_agg(const float* __restrict__ pos,
                                             const int* __restrict__ types,
                                             const float* __restrict__ emb,
                                             float* __restrict__ agg) {
  __shared__ float sw[TI][MAXE];
  __shared__ int   srow[TI][MAXE];
  __shared__ int   scnt[TI];
  const int tid = threadIdx.x;
  const int i0 = blockIdx.x * TI;
  if (tid < TI) scnt[tid] = 0;

  float pix[TI], piy[TI], piz[TI];
#pragma unroll
  for (int m = 0; m < TI; ++m) {   // uniform addresses -> scalar loads
    pix[m] = 10.0f * pos[(i0 + m) * 3 + 0];
    piy[m] = 10.0f * pos[(i0 + m) * 3 + 1];
    piz[m] = 10.0f * pos[(i0 + m) * 3 + 2];
  }
  __syncthreads();

  for (int j = tid; j < NATOMS; j += 256) {
    float pjx = 10.0f * pos[j * 3 + 0];
    float pjy = 10.0f * pos[j * 3 + 1];
    float pjz = 10.0f * pos[j * 3 + 2];
#pragma unroll
    for (int m = 0; m < TI; ++m) {
      float dx = pix[m] - pjx, dy = piy[m] - pjy, dz = piz[m] - pjz;
      float d2 = dx * dx;
      d2 = fmaf(dy, dy, d2);
      d2 = fmaf(dz, dz, d2);
      // ref mask: d2 > 1e-12 && sqrt(d2) <= 5  <=>  1e-12 < d2 <= 25 (fp32-exact)
      if (d2 > 1e-12f && d2 <= 25.0f) {
        float w = __expf(-sqrtf(d2));
        int e = atomicAdd(&scnt[m], 1);
        if (e < MAXE) {
          sw[m][e] = w;
          srow[m][e] = types[j] * DD;
        }
      }
    }
  }
  __syncthreads();

  // 256 threads = 2 groups of 128 dims; group g handles atoms {g, g+2}
  const int d = tid & (DD - 1);
  const int g = tid >> 7;
#pragma unroll
  for (int mm = 0; mm < TI; mm += 2) {
    int m = g + mm;
    int nc = min(scnt[m], MAXE);
    float a = 0.0f;
    for (int e = 0; e < nc; ++e)
      a = fmaf(sw[m][e], emb[srow[m][e] + d], a);
    agg[(size_t)(i0 + m) * DD + d] = a;
  }
}

// MLP: e_node = relu([h,agg] @ W1) @ w2, summed into out (kcal/mol).
// MB=32 nodes/block, 512 threads, grid=256 (1 block/CU). Thread
// (tx=tid&63, my=tid>>6) computes hidden 4tx..4tx+3 for nodes 4my..4my+3:
// per j = 1 dwordx4 W1 (coalesced 1KB/wave) + 1 uniform ds_read_b128
// (broadcast) + 16 FMA  -> 3x fewer mem instructions per FMA than before.
__global__ __launch_bounds__(MTH, 2) void k_mlp(const int* __restrict__ types,
                                                const float* __restrict__ emb,
                                                const float* __restrict__ agg,
                                                const float* __restrict__ W1,
                                                const float* __restrict__ w2,
                                                float* __restrict__ out) {
  __shared__ float sf[2 * DD][MB];  // feat transposed [j][m], 32 KB
  __shared__ float sred[MTH / 64];
  const int tid = threadIdx.x;
  const int n0 = blockIdx.x * MB;

  // stage feat = concat(h, agg), float4-coalesced along j:
  // thread: fixed m = tid&31; jb = (tid>>5) + 16k covers 0..63 (j = 4*jb..+3).
  // LDS writes: bank = m -> 32 banks, 2 lanes/bank (different addr) = free.
  {
    const int m = tid & 31;
    const int node = n0 + m;
    const int jb0 = tid >> 5;          // 0..15
    const int trow = types[node] * DD; // hoisted, scalar-ish
#pragma unroll
    for (int k = 0; k < 4; ++k) {
      int jb = jb0 + 16 * k;           // 0..63
      float4 v;
      if (jb < 32) v = *(const float4*)&emb[trow + 4 * jb];
      else         v = *(const float4*)&agg[(size_t)node * DD + 4 * (jb - 32)];
      int j0 = 4 * jb;
      sf[j0 + 0][m] = v.x;
      sf[j0 + 1][m] = v.y;
      sf[j0 + 2][m] = v.z;
      sf[j0 + 3][m] = v.w;
    }
  }
  __syncthreads();

  const int tx = tid & 63;   // hidden block h = 4*tx .. 4*tx+3
  const int my = tid >> 6;   // 0..7 -> nodes 4*my .. 4*my+3
  float acc[4][4];           // [r: node][q: hidden]
#pragma unroll
  for (int r = 0; r < 4; ++r)
#pragma unroll
    for (int q = 0; q < 4; ++q) acc[r][q] = 0.0f;

  const float* fb = &sf[0][4 * my];
  const float* wp = &W1[4 * tx];
#pragma unroll 4
  for (int j = 0; j < 2 * DD; ++j) {
    float w[4], f[4];
    *(float4*)&w[0] = *(const float4*)(wp + j * HH);   // coalesced dwordx4
    *(float4*)&f[0] = *(const float4*)(fb + j * MB);   // uniform broadcast
#pragma unroll
    for (int r = 0; r < 4; ++r)
#pragma unroll
      for (int q = 0; q < 4; ++q)
        acc[r][q] = fmaf(f[r], w[q], acc[r][q]);
  }

  float wq[4];
  *(float4*)&wq[0] = *(const float4*)&w2[4 * tx];
  float p = 0.0f;
#pragma unroll
  for (int r = 0; r < 4; ++r)
#pragma unroll
    for (int q = 0; q < 4; ++q)
      p += fmaxf(acc[r][q], 0.0f) * wq[q];

#pragma unroll
  for (int off = 32; off; off >>= 1) p += __shfl_down(p, off);  // wave64 reduce
  if ((tid & 63) == 0) sred[tid >> 6] = p;
  __syncthreads();
  if (tid == 0) {
    float t = 0.0f;
#pragma unroll
    for (int q = 0; q < MTH / 64; ++q) t += sred[q];
    atomicAdd(out, t * 0.2390057361376673f);
  }
}

extern "C" void kernel_launch(void* const* d_in, const int* in_sizes, int n_in,
                              void* d_out, int out_size, void* d_ws, size_t ws_size,
                              hipStream_t stream) {
  const float* pos = (const float*)d_in[0];
  const int*   typ = (const int*)d_in[1];
  const float* emb = (const float*)d_in[2];
  const float* W1  = (const float*)d_in[3];
  const float* w2  = (const float*)d_in[4];
  float* out = (float*)d_out;
  float* agg = (float*)d_ws;  // 8192*128 floats = 4 MB scratch

  hipLaunchKernelGGL(k_zero, dim3(1), dim3(64), 0, stream, out);
  hipLaunchKernelGGL(k_agg, dim3(NATOMS / TI), dim3(256), 0, stream,
                     pos, typ, emb, agg);
  hipLaunchKernelGGL(k_mlp, dim3(NATOMS / MB), dim3(MTH), 0, stream,
                     typ, emb, agg, W1, w2, out);
}

// Round 4
// 100.223 us; speedup vs baseline: 1.2407x; 1.1666x over previous
//
#include <hip/hip_runtime.h>

#define NATOMS 8192
#define DD 128     // embedding dim
#define HH 256     // hidden dim
#define TI 4       // atoms per block in aggregation (verbatim structure)
#define MAXE 128   // max edges per atom (mean ~20, Poisson; 128 is >>6 sigma)
#define BM 32      // nodes per block in MFMA MLP
#define KJ2KCAL 0.2390057361376673f

typedef __attribute__((ext_vector_type(8))) short bf16x8;  // 4 VGPRs
typedef __attribute__((ext_vector_type(4))) float f32x4;

// fp32 -> bf16 round-to-nearest-even (finite inputs)
__device__ inline unsigned short f2bf(float x) {
  unsigned int b = __builtin_bit_cast(unsigned int, x);
  b += 0x7FFFu + ((b >> 16) & 1u);
  return (unsigned short)(b >> 16);
}

// One-time prep: W1bfT[n][k] = bf16(W1[k][n]) (128 KB, L2-resident after first
// touch), and zero the poisoned output scalar. grid 64 x 256.
__global__ void k_prep(const float* __restrict__ W1, unsigned short* __restrict__ W1bfT,
                       float* __restrict__ out) {
  if (blockIdx.x == 0 && threadIdx.x == 0) out[0] = 0.0f;
  int t = blockIdx.x * 256 + threadIdx.x;   // 0..16383
  int n = t & 255;
  int kb = (t >> 8) * 4;                    // 0,4,..,252
#pragma unroll
  for (int i = 0; i < 4; ++i)
    W1bfT[n * HH + kb + i] = f2bf(W1[(kb + i) * HH + n]);  // read coalesced in n
}

// One block handles TI atoms: O(N) distance sweep, compact valid edges
// (w = exp(-d), row = type[j]*DD) into LDS lists, then sparse-aggregate
// agg[i][:] = sum_e w_e * emb[row_e][:].  [verbatim except bf16 final store]
__global__ __launch_bounds__(256) void k_agg(const float* __restrict__ pos,
                                             const int* __restrict__ types,
                                             const float* __restrict__ emb,
                                             unsigned short* __restrict__ aggbf) {
  __shared__ float sw[TI][MAXE];
  __shared__ int   srow[TI][MAXE];
  __shared__ int   scnt[TI];
  const int tid = threadIdx.x;
  const int i0 = blockIdx.x * TI;
  if (tid < TI) scnt[tid] = 0;

  float pix[TI], piy[TI], piz[TI];
#pragma unroll
  for (int m = 0; m < TI; ++m) {   // uniform addresses -> scalar loads
    pix[m] = 10.0f * pos[(i0 + m) * 3 + 0];
    piy[m] = 10.0f * pos[(i0 + m) * 3 + 1];
    piz[m] = 10.0f * pos[(i0 + m) * 3 + 2];
  }
  __syncthreads();

  for (int j = tid; j < NATOMS; j += 256) {
    float pjx = 10.0f * pos[j * 3 + 0];
    float pjy = 10.0f * pos[j * 3 + 1];
    float pjz = 10.0f * pos[j * 3 + 2];
#pragma unroll
    for (int m = 0; m < TI; ++m) {
      float dx = pix[m] - pjx, dy = piy[m] - pjy, dz = piz[m] - pjz;
      float d2 = dx * dx;
      d2 = fmaf(dy, dy, d2);
      d2 = fmaf(dz, dz, d2);
      // ref mask: d2 > 1e-12 && sqrt(d2) <= 5  <=>  1e-12 < d2 <= 25 (fp32-exact)
      if (d2 > 1e-12f && d2 <= 25.0f) {
        float w = __expf(-sqrtf(d2));
        int e = atomicAdd(&scnt[m], 1);
        if (e < MAXE) {
          sw[m][e] = w;
          srow[m][e] = types[j] * DD;
        }
      }
    }
  }
  __syncthreads();

  // 256 threads = 2 groups of 128 dims; group g handles atoms {g, g+2}
  const int d = tid & (DD - 1);
  const int g = tid >> 7;
#pragma unroll
  for (int mm = 0; mm < TI; mm += 2) {
    int m = g + mm;
    int nc = min(scnt[m], MAXE);
    float a = 0.0f;
    for (int e = 0; e < nc; ++e)
      a = fmaf(sw[m][e], emb[srow[m][e] + d], a);
    aggbf[(size_t)(i0 + m) * DD + d] = f2bf(a);   // feat is bf16 downstream anyway
  }
}

// MFMA MLP: hidden = feat @ W1 (bf16 in, f32 acc), then sum(relu(hidden)*w2).
// 256 blocks x 512 threads (8 waves). Block stages feat[BM=32][256] bf16 in
// LDS (rows padded to 264 -> 2-way banks on b128 reads). Wave w owns N-slice
// [32w, 32w+32): 2 Mx2 N tiles x 8 K-steps of mfma_f32_16x16x32_bf16.
// B-frags read straight from L2-resident W1bfT (no LDS). Epilogue: total
// energy only -> lane n = tile_base + (lane&15) (m89-verified D col layout);
// M-row mapping cancels under the full sum.
__global__ __launch_bounds__(512, 2) void k_mlp(const int* __restrict__ types,
                                                const float* __restrict__ emb,
                                                const unsigned short* __restrict__ aggbf,
                                                const unsigned short* __restrict__ W1bfT,
                                                const float* __restrict__ w2,
                                                float* __restrict__ out) {
  __shared__ unsigned short sA[BM][264];  // 16.5 KB, +8 pad -> stride 132 dw = 4 mod 32
  __shared__ float sred[8];
  const int tid = threadIdx.x;
  const int n0 = blockIdx.x * BM;

  // stage feat = concat(emb[type], aggbf) as bf16: 32 rows x 64 chunks of 4
  for (int idx = tid; idx < BM * 64; idx += 512) {
    int row = idx >> 6;
    int cb = idx & 63;          // 4-col chunk
    int node = n0 + row;
    ushort4 u;
    if (cb < 32) {
      float4 v = *(const float4*)&emb[types[node] * DD + 4 * cb];
      u.x = f2bf(v.x); u.y = f2bf(v.y); u.z = f2bf(v.z); u.w = f2bf(v.w);
    } else {
      u = *(const ushort4*)&aggbf[(size_t)node * DD + 4 * (cb - 32)];
    }
    *(ushort4*)&sA[row][4 * cb] = u;
  }
  __syncthreads();

  const int lane = tid & 63;
  const int wv = tid >> 6;      // 0..7 -> N-slice
  const int nb = wv * 32;
  const int l15 = lane & 15;
  const int g = lane >> 4;      // 0..3 -> k-subgroup
  f32x4 acc00 = {}, acc01 = {}, acc10 = {}, acc11 = {};

  const unsigned short* bp0 = W1bfT + (nb + l15) * HH + 8 * g;
  const unsigned short* bp1 = bp0 + 16 * HH;
#pragma unroll
  for (int ks = 0; ks < 8; ++ks) {
    bf16x8 a0 = *(const bf16x8*)&sA[l15][ks * 32 + 8 * g];
    bf16x8 a1 = *(const bf16x8*)&sA[16 + l15][ks * 32 + 8 * g];
    bf16x8 b0 = *(const bf16x8*)(bp0 + ks * 32);
    bf16x8 b1 = *(const bf16x8*)(bp1 + ks * 32);
    acc00 = __builtin_amdgcn_mfma_f32_16x16x32_bf16(a0, b0, acc00, 0, 0, 0);
    acc01 = __builtin_amdgcn_mfma_f32_16x16x32_bf16(a0, b1, acc01, 0, 0, 0);
    acc10 = __builtin_amdgcn_mfma_f32_16x16x32_bf16(a1, b0, acc10, 0, 0, 0);
    acc11 = __builtin_amdgcn_mfma_f32_16x16x32_bf16(a1, b1, acc11, 0, 0, 0);
  }

  const float w2a = w2[nb + l15];
  const float w2b = w2[nb + 16 + l15];
  float p = 0.0f;
#pragma unroll
  for (int i = 0; i < 4; ++i) {
    p += fmaxf(acc00[i], 0.0f) * w2a;
    p += fmaxf(acc10[i], 0.0f) * w2a;
    p += fmaxf(acc01[i], 0.0f) * w2b;
    p += fmaxf(acc11[i], 0.0f) * w2b;
  }
#pragma unroll
  for (int off = 32; off; off >>= 1) p += __shfl_down(p, off);  // wave64 reduce
  if (lane == 0) sred[wv] = p;
  __syncthreads();
  if (tid == 0) {
    float t = 0.0f;
#pragma unroll
    for (int q = 0; q < 8; ++q) t += sred[q];
    atomicAdd(out, t * KJ2KCAL);
  }
}

extern "C" void kernel_launch(void* const* d_in, const int* in_sizes, int n_in,
                              void* d_out, int out_size, void* d_ws, size_t ws_size,
                              hipStream_t stream) {
  const float* pos = (const float*)d_in[0];
  const int*   typ = (const int*)d_in[1];
  const float* emb = (const float*)d_in[2];
  const float* W1  = (const float*)d_in[3];
  const float* w2  = (const float*)d_in[4];
  float* out = (float*)d_out;
  unsigned short* aggbf = (unsigned short*)d_ws;                     // 2 MB
  unsigned short* W1bfT = (unsigned short*)((char*)d_ws + NATOMS * DD * 2);  // 128 KB

  hipLaunchKernelGGL(k_prep, dim3(64), dim3(256), 0, stream, W1, W1bfT, out);
  hipLaunchKernelGGL(k_agg, dim3(NATOMS / TI), dim3(256), 0, stream,
                     pos, typ, emb, aggbf);
  hipLaunchKernelGGL(k_mlp, dim3(NATOMS / BM), dim3(512), 0, stream,
                     typ, emb, aggbf, W1bfT, w2, out);
}

// Round 8
// 100.171 us; speedup vs baseline: 1.2413x; 1.0005x over previous
//
#include <hip/hip_runtime.h>

#define NATOMS 8192
#define DD 128     // embedding dim
#define HH 256     // hidden dim
#define TI 4       // atoms per block in aggregation (verified value — FROZEN)
#define MAXE 128   // max edges per atom (mean ~20, Poisson; 128 is >>6 sigma)
#define BM 32      // nodes per block in MFMA MLP
#define KJ2KCAL 0.2390057361376673f

typedef __attribute__((ext_vector_type(8))) short bf16x8;  // 4 VGPRs
typedef __attribute__((ext_vector_type(4))) float f32x4;

// fp32 -> bf16 round-to-nearest-even (finite inputs)
__device__ inline unsigned short f2bf(float x) {
  unsigned int b = __builtin_bit_cast(unsigned int, x);
  b += 0x7FFFu + ((b >> 16) & 1u);
  return (unsigned short)(b >> 16);
}

// One-time prep: W1bfT[n][k] = bf16(W1[k][n]) (128 KB, L2-resident after first
// touch), and zero the poisoned output scalar. grid 64 x 256.
__global__ void k_prep(const float* __restrict__ W1, unsigned short* __restrict__ W1bfT,
                       float* __restrict__ out) {
  if (blockIdx.x == 0 && threadIdx.x == 0) out[0] = 0.0f;
  int t = blockIdx.x * 256 + threadIdx.x;   // 0..16383
  int n = t & 255;
  int kb = (t >> 8) * 4;                    // 0,4,..,252
#pragma unroll
  for (int i = 0; i < 4; ++i)
    W1bfT[n * HH + kb + i] = f2bf(W1[(kb + i) * HH + n]);  // read coalesced in n
}

// One block handles TI atoms: O(N) distance sweep, compact valid edges
// (w = exp(-d), row = type[j]*DD) into LDS lists, then sparse-aggregate
// agg[i][:] = sum_e w_e * emb[row_e][:].  [verified round-4 source, FROZEN:
// TI=8 (R7), pos4 handoff (R5/R6), and fused TI=16 (R1) each produced
// deterministic absmax 11-22 despite on-paper value equivalence. Do not
// modify this kernel without a mechanism-level explanation.]
__global__ __launch_bounds__(256) void k_agg(const float* __restrict__ pos,
                                             const int* __restrict__ types,
                                             const float* __restrict__ emb,
                                             unsigned short* __restrict__ aggbf) {
  __shared__ float sw[TI][MAXE];
  __shared__ int   srow[TI][MAXE];
  __shared__ int   scnt[TI];
  const int tid = threadIdx.x;
  const int i0 = blockIdx.x * TI;
  if (tid < TI) scnt[tid] = 0;

  float pix[TI], piy[TI], piz[TI];
#pragma unroll
  for (int m = 0; m < TI; ++m) {   // uniform addresses -> scalar loads
    pix[m] = 10.0f * pos[(i0 + m) * 3 + 0];
    piy[m] = 10.0f * pos[(i0 + m) * 3 + 1];
    piz[m] = 10.0f * pos[(i0 + m) * 3 + 2];
  }
  __syncthreads();

  for (int j = tid; j < NATOMS; j += 256) {
    float pjx = 10.0f * pos[j * 3 + 0];
    float pjy = 10.0f * pos[j * 3 + 1];
    float pjz = 10.0f * pos[j * 3 + 2];
#pragma unroll
    for (int m = 0; m < TI; ++m) {
      float dx = pix[m] - pjx, dy = piy[m] - pjy, dz = piz[m] - pjz;
      float d2 = dx * dx;
      d2 = fmaf(dy, dy, d2);
      d2 = fmaf(dz, dz, d2);
      // ref mask: d2 > 1e-12 && sqrt(d2) <= 5  <=>  1e-12 < d2 <= 25 (fp32-exact)
      if (d2 > 1e-12f && d2 <= 25.0f) {
        float w = __expf(-sqrtf(d2));
        int e = atomicAdd(&scnt[m], 1);
        if (e < MAXE) {
          sw[m][e] = w;
          srow[m][e] = types[j] * DD;
        }
      }
    }
  }
  __syncthreads();

  // 256 threads = 2 groups of 128 dims; group g handles atoms {g, g+2}
  const int d = tid & (DD - 1);
  const int g = tid >> 7;
#pragma unroll
  for (int mm = 0; mm < TI; mm += 2) {
    int m = g + mm;
    int nc = min(scnt[m], MAXE);
    float a = 0.0f;
    for (int e = 0; e < nc; ++e)
      a = fmaf(sw[m][e], emb[srow[m][e] + d], a);
    aggbf[(size_t)(i0 + m) * DD + d] = f2bf(a);   // feat is bf16 downstream anyway
  }
}

// MFMA MLP [verified round 4, unchanged]: hidden = feat @ W1 (bf16 in, f32
// acc), then sum(relu(hidden)*w2). 256 blocks x 512 threads (8 waves). Block
// stages feat[BM=32][256] bf16 in LDS (rows padded to 264 -> 2-way banks on
// b128 reads). Wave w owns N-slice [32w,32w+32): 2Mx2N tiles x 8 K-steps of
// mfma_f32_16x16x32_bf16; B-frags straight from L2-resident W1bfT.
__global__ __launch_bounds__(512, 2) void k_mlp(const int* __restrict__ types,
                                                const float* __restrict__ emb,
                                                const unsigned short* __restrict__ aggbf,
                                                const unsigned short* __restrict__ W1bfT,
                                                const float* __restrict__ w2,
                                                float* __restrict__ out) {
  __shared__ unsigned short sA[BM][264];  // 16.5 KB
  __shared__ float sred[8];
  const int tid = threadIdx.x;
  const int n0 = blockIdx.x * BM;

  // stage feat = concat(emb[type], aggbf) as bf16: 32 rows x 64 chunks of 4
  for (int idx = tid; idx < BM * 64; idx += 512) {
    int row = idx >> 6;
    int cb = idx & 63;          // 4-col chunk
    int node = n0 + row;
    ushort4 u;
    if (cb < 32) {
      float4 v = *(const float4*)&emb[types[node] * DD + 4 * cb];
      u.x = f2bf(v.x); u.y = f2bf(v.y); u.z = f2bf(v.z); u.w = f2bf(v.w);
    } else {
      u = *(const ushort4*)&aggbf[(size_t)node * DD + 4 * (cb - 32)];
    }
    *(ushort4*)&sA[row][4 * cb] = u;
  }
  __syncthreads();

  const int lane = tid & 63;
  const int wv = tid >> 6;      // 0..7 -> N-slice
  const int nb = wv * 32;
  const int l15 = lane & 15;
  const int g = lane >> 4;      // 0..3 -> k-subgroup
  f32x4 acc00 = {}, acc01 = {}, acc10 = {}, acc11 = {};

  const unsigned short* bp0 = W1bfT + (nb + l15) * HH + 8 * g;
  const unsigned short* bp1 = bp0 + 16 * HH;
#pragma unroll
  for (int ks = 0; ks < 8; ++ks) {
    bf16x8 a0 = *(const bf16x8*)&sA[l15][ks * 32 + 8 * g];
    bf16x8 a1 = *(const bf16x8*)&sA[16 + l15][ks * 32 + 8 * g];
    bf16x8 b0 = *(const bf16x8*)(bp0 + ks * 32);
    bf16x8 b1 = *(const bf16x8*)(bp1 + ks * 32);
    acc00 = __builtin_amdgcn_mfma_f32_16x16x32_bf16(a0, b0, acc00, 0, 0, 0);
    acc01 = __builtin_amdgcn_mfma_f32_16x16x32_bf16(a0, b1, acc01, 0, 0, 0);
    acc10 = __builtin_amdgcn_mfma_f32_16x16x32_bf16(a1, b0, acc10, 0, 0, 0);
    acc11 = __builtin_amdgcn_mfma_f32_16x16x32_bf16(a1, b1, acc11, 0, 0, 0);
  }

  const float w2a = w2[nb + l15];
  const float w2b = w2[nb + 16 + l15];
  float p = 0.0f;
#pragma unroll
  for (int i = 0; i < 4; ++i) {
    p += fmaxf(acc00[i], 0.0f) * w2a;
    p += fmaxf(acc10[i], 0.0f) * w2a;
    p += fmaxf(acc01[i], 0.0f) * w2b;
    p += fmaxf(acc11[i], 0.0f) * w2b;
  }
#pragma unroll
  for (int off = 32; off; off >>= 1) p += __shfl_down(p, off);  // wave64 reduce
  if (lane == 0) sred[wv] = p;
  __syncthreads();
  if (tid == 0) {
    float t = 0.0f;
#pragma unroll
    for (int q = 0; q < 8; ++q) t += sred[q];
    atomicAdd(out, t * KJ2KCAL);
  }
}

extern "C" void kernel_launch(void* const* d_in, const int* in_sizes, int n_in,
                              void* d_out, int out_size, void* d_ws, size_t ws_size,
                              hipStream_t stream) {
  const float* pos = (const float*)d_in[0];
  const int*   typ = (const int*)d_in[1];
  const float* emb = (const float*)d_in[2];
  const float* W1  = (const float*)d_in[3];
  const float* w2  = (const float*)d_in[4];
  float* out = (float*)d_out;
  unsigned short* aggbf = (unsigned short*)d_ws;                              // 2 MB
  unsigned short* W1bfT = (unsigned short*)((char*)d_ws + (2u << 20));        // 128 KB

  hipLaunchKernelGGL(k_prep, dim3(64), dim3(256), 0, stream, W1, W1bfT, out);
  hipLaunchKernelGGL(k_agg, dim3(NATOMS / TI), dim3(256), 0, stream,
                     pos, typ, emb, aggbf);
  hipLaunchKernelGGL(k_mlp, dim3(NATOMS / BM), dim3(512), 0, stream,
                     typ, emb, aggbf, W1bfT, w2, out);
}

// Round 9
// 99.790 us; speedup vs baseline: 1.2460x; 1.0038x over previous
//
#include <hip/hip_runtime.h>

#define NATOMS 8192
#define DD 128     // embedding dim
#define HH 256     // hidden dim
#define TI 4       // atoms per block in aggregation
#define MAXE 128   // max edges per atom (mean ~20, Poisson; 128 is >>6 sigma)
#define BM 32      // nodes per block in MFMA MLP
#define KJ2KCAL 0.2390057361376673f

typedef __attribute__((ext_vector_type(8))) short bf16x8;  // 4 VGPRs
typedef __attribute__((ext_vector_type(4))) float f32x4;

// fp32 -> bf16 round-to-nearest-even (finite inputs)
__device__ inline unsigned short f2bf(float x) {
  unsigned int b = __builtin_bit_cast(unsigned int, x);
  b += 0x7FFFu + ((b >> 16) & 1u);
  return (unsigned short)(b >> 16);
}

// One-time prep [verified, unchanged]: W1bfT[n][k] = bf16(W1[k][n]) (128 KB,
// L2-resident after first touch), and zero the poisoned output scalar.
__global__ void k_prep(const float* __restrict__ W1, unsigned short* __restrict__ W1bfT,
                       float* __restrict__ out) {
  if (blockIdx.x == 0 && threadIdx.x == 0) out[0] = 0.0f;
  int t = blockIdx.x * 256 + threadIdx.x;   // 0..16383
  int n = t & 255;
  int kb = (t >> 8) * 4;                    // 0,4,..,252
#pragma unroll
  for (int i = 0; i < 4; ++i)
    W1bfT[n * HH + kb + i] = f2bf(W1[(kb + i) * HH + n]);  // read coalesced in n
}

// One block = TI=4 atoms. Sweep now stores only a 64-bit ballot per (m, chunk)
// (1 uniform LDS store/wave) instead of the divergent exp/atomic/store body
// (~15 instrs at ~1.5/64 lanes, ~79% of (m,j) wave-iters -- the diagnosed 2.5x
// bloat). A post-pass (wave m owns atom m) scans+expands the masks into the
// SAME compacted lists, recomputing d2/w with textually identical expressions
// -> identical edge set, bit-identical weights/rows; order = j-ascending
// (reorder effect on E proven < ~0.5 << threshold). Phase-2 verbatim.
__global__ __launch_bounds__(256) void k_agg(const float* __restrict__ pos,
                                             const int* __restrict__ types,
                                             const float* __restrict__ emb,
                                             unsigned short* __restrict__ aggbf) {
  __shared__ unsigned long long smask[TI][NATOMS / 64];  // 4 KB
  __shared__ float sw[TI][MAXE];
  __shared__ int   srow[TI][MAXE];
  __shared__ int   scnt[TI];
  const int tid = threadIdx.x;
  const int i0 = blockIdx.x * TI;

  float pix[TI], piy[TI], piz[TI];
#pragma unroll
  for (int m = 0; m < TI; ++m) {   // uniform addresses -> scalar loads
    pix[m] = 10.0f * pos[(i0 + m) * 3 + 0];
    piy[m] = 10.0f * pos[(i0 + m) * 3 + 1];
    piz[m] = 10.0f * pos[(i0 + m) * 3 + 2];
  }

  // sweep: lanes of a wave cover 64 consecutive j -> ballot bit r <-> j=64c+r
  for (int j = tid; j < NATOMS; j += 256) {
    float pjx = 10.0f * pos[j * 3 + 0];
    float pjy = 10.0f * pos[j * 3 + 1];
    float pjz = 10.0f * pos[j * 3 + 2];
    int c = j >> 6;                // wave-uniform chunk id
#pragma unroll
    for (int m = 0; m < TI; ++m) {
      float dx = pix[m] - pjx, dy = piy[m] - pjy, dz = piz[m] - pjz;
      float d2 = dx * dx;
      d2 = fmaf(dy, dy, d2);
      d2 = fmaf(dz, dz, d2);
      // ref mask: d2 > 1e-12 && sqrt(d2) <= 5  <=>  1e-12 < d2 <= 25 (fp32-exact)
      unsigned long long bal = __ballot(d2 > 1e-12f && d2 <= 25.0f);
      if ((tid & 63) == 0) smask[m][c] = bal;
    }
  }
  __syncthreads();

  // scan + expand: wave m handles atom m. Lane l owns chunks {2l, 2l+1}.
  {
    const int m = tid >> 6;        // 0..3 (4 waves)
    const int l = tid & 63;
    unsigned long long mA = smask[m][2 * l];
    unsigned long long mB = smask[m][2 * l + 1];
    int cA = __popcll(mA), cB = __popcll(mB);
    int s = cA + cB;
    int scan = s;                  // inclusive prefix over 64 lanes
#pragma unroll
    for (int off = 1; off < 64; off <<= 1) {
      int t = __shfl_up(scan, off);
      if (l >= off) scan += t;
    }
    int excl = scan - s;
    if (l == 63) scnt[m] = scan;   // per-atom total
    // same-source distance/weight recompute (bit-identical values)
    float px = 10.0f * pos[(i0 + m) * 3 + 0];
    float py = 10.0f * pos[(i0 + m) * 3 + 1];
    float pz = 10.0f * pos[(i0 + m) * 3 + 2];
#pragma unroll
    for (int h = 0; h < 2; ++h) {
      unsigned long long mask = h ? mB : mA;
      int base = h ? excl + cA : excl;
      int cbase = 64 * (2 * l + h);
      while (mask) {
        int r = __ffsll((long long)mask) - 1;
        mask &= mask - 1;
        int j = cbase + r;
        if (base < MAXE) {
          float pjx = 10.0f * pos[j * 3 + 0];
          float pjy = 10.0f * pos[j * 3 + 1];
          float pjz = 10.0f * pos[j * 3 + 2];
          float dx = px - pjx, dy = py - pjy, dz = pz - pjz;
          float d2 = dx * dx;
          d2 = fmaf(dy, dy, d2);
          d2 = fmaf(dz, dz, d2);
          float w = __expf(-sqrtf(d2));
          sw[m][base] = w;
          srow[m][base] = types[j] * DD;
        }
        ++base;
      }
    }
  }
  __syncthreads();

  // phase 2 [verbatim]: 256 threads = 2 groups of 128 dims; group g -> {g, g+2}
  const int d = tid & (DD - 1);
  const int g = tid >> 7;
#pragma unroll
  for (int mm = 0; mm < TI; mm += 2) {
    int m = g + mm;
    int nc = min(scnt[m], MAXE);
    float a = 0.0f;
    for (int e = 0; e < nc; ++e)
      a = fmaf(sw[m][e], emb[srow[m][e] + d], a);
    aggbf[(size_t)(i0 + m) * DD + d] = f2bf(a);   // feat is bf16 downstream anyway
  }
}

// MFMA MLP [verified, unchanged]: hidden = feat @ W1 (bf16 in, f32 acc), then
// sum(relu(hidden)*w2). 256 blocks x 512 threads (8 waves). Block stages
// feat[BM=32][256] bf16 in LDS (rows padded to 264 -> 2-way banks on b128
// reads). Wave w owns N-slice [32w,32w+32): 2Mx2N tiles x 8 K-steps of
// mfma_f32_16x16x32_bf16; B-frags straight from L2-resident W1bfT.
__global__ __launch_bounds__(512, 2) void k_mlp(const int* __restrict__ types,
                                                const float* __restrict__ emb,
                                                const unsigned short* __restrict__ aggbf,
                                                const unsigned short* __restrict__ W1bfT,
                                                const float* __restrict__ w2,
                                                float* __restrict__ out) {
  __shared__ unsigned short sA[BM][264];  // 16.5 KB
  __shared__ float sred[8];
  const int tid = threadIdx.x;
  const int n0 = blockIdx.x * BM;

  // stage feat = concat(emb[type], aggbf) as bf16: 32 rows x 64 chunks of 4
  for (int idx = tid; idx < BM * 64; idx += 512) {
    int row = idx >> 6;
    int cb = idx & 63;          // 4-col chunk
    int node = n0 + row;
    ushort4 u;
    if (cb < 32) {
      float4 v = *(const float4*)&emb[types[node] * DD + 4 * cb];
      u.x = f2bf(v.x); u.y = f2bf(v.y); u.z = f2bf(v.z); u.w = f2bf(v.w);
    } else {
      u = *(const ushort4*)&aggbf[(size_t)node * DD + 4 * (cb - 32)];
    }
    *(ushort4*)&sA[row][4 * cb] = u;
  }
  __syncthreads();

  const int lane = tid & 63;
  const int wv = tid >> 6;      // 0..7 -> N-slice
  const int nb = wv * 32;
  const int l15 = lane & 15;
  const int g = lane >> 4;      // 0..3 -> k-subgroup
  f32x4 acc00 = {}, acc01 = {}, acc10 = {}, acc11 = {};

  const unsigned short* bp0 = W1bfT + (nb + l15) * HH + 8 * g;
  const unsigned short* bp1 = bp0 + 16 * HH;
#pragma unroll
  for (int ks = 0; ks < 8; ++ks) {
    bf16x8 a0 = *(const bf16x8*)&sA[l15][ks * 32 + 8 * g];
    bf16x8 a1 = *(const bf16x8*)&sA[16 + l15][ks * 32 + 8 * g];
    bf16x8 b0 = *(const bf16x8*)(bp0 + ks * 32);
    bf16x8 b1 = *(const bf16x8*)(bp1 + ks * 32);
    acc00 = __builtin_amdgcn_mfma_f32_16x16x32_bf16(a0, b0, acc00, 0, 0, 0);
    acc01 = __builtin_amdgcn_mfma_f32_16x16x32_bf16(a0, b1, acc01, 0, 0, 0);
    acc10 = __builtin_amdgcn_mfma_f32_16x16x32_bf16(a1, b0, acc10, 0, 0, 0);
    acc11 = __builtin_amdgcn_mfma_f32_16x16x32_bf16(a1, b1, acc11, 0, 0, 0);
  }

  const float w2a = w2[nb + l15];
  const float w2b = w2[nb + 16 + l15];
  float p = 0.0f;
#pragma unroll
  for (int i = 0; i < 4; ++i) {
    p += fmaxf(acc00[i], 0.0f) * w2a;
    p += fmaxf(acc10[i], 0.0f) * w2a;
    p += fmaxf(acc01[i], 0.0f) * w2b;
    p += fmaxf(acc11[i], 0.0f) * w2b;
  }
#pragma unroll
  for (int off = 32; off; off >>= 1) p += __shfl_down(p, off);  // wave64 reduce
  if (lane == 0) sred[wv] = p;
  __syncthreads();
  if (tid == 0) {
    float t = 0.0f;
#pragma unroll
    for (int q = 0; q < 8; ++q) t += sred[q];
    atomicAdd(out, t * KJ2KCAL);
  }
}

extern "C" void kernel_launch(void* const* d_in, const int* in_sizes, int n_in,
                              void* d_out, int out_size, void* d_ws, size_t ws_size,
                              hipStream_t stream) {
  const float* pos = (const float*)d_in[0];
  const int*   typ = (const int*)d_in[1];
  const float* emb = (const float*)d_in[2];
  const float* W1  = (const float*)d_in[3];
  const float* w2  = (const float*)d_in[4];
  float* out = (float*)d_out;
  unsigned short* aggbf = (unsigned short*)d_ws;                        // 2 MB
  unsigned short* W1bfT = (unsigned short*)((char*)d_ws + (2u << 20));  // 128 KB

  hipLaunchKernelGGL(k_prep, dim3(64), dim3(256), 0, stream, W1, W1bfT, out);
  hipLaunchKernelGGL(k_agg, dim3(NATOMS / TI), dim3(256), 0, stream,
                     pos, typ, emb, aggbf);
  hipLaunchKernelGGL(k_mlp, dim3(NATOMS / BM), dim3(512), 0, stream,
                     typ, emb, aggbf, W1bfT, w2, out);
}

// Round 10
// 98.197 us; speedup vs baseline: 1.2663x; 1.0162x over previous
//
#include <hip/hip_runtime.h>

#define NATOMS 8192
#define DD 128     // embedding dim
#define HH 256     // hidden dim
#define TI 4       // atoms per block in aggregation
#define MAXE 128   // max edges per atom (mean ~20, Poisson; 128 is >>6 sigma)
#define BM 32      // nodes per block in MFMA MLP
#define KJ2KCAL 0.2390057361376673f

typedef __attribute__((ext_vector_type(8))) short bf16x8;  // 4 VGPRs
typedef __attribute__((ext_vector_type(4))) float f32x4;

// fp32 -> bf16 round-to-nearest-even (finite inputs)
__device__ inline unsigned short f2bf(float x) {
  unsigned int b = __builtin_bit_cast(unsigned int, x);
  b += 0x7FFFu + ((b >> 16) & 1u);
  return (unsigned short)(b >> 16);
}

// k_agg with k_prep merged in (one fewer launch):
//  - blocks 0..63 additionally transpose W1 -> bf16 W1bfT (identical values to
//    the verified k_prep); block 0 zeroes the poisoned output scalar. k_mlp
//    launched after this kernel sees both (in-stream kernel-boundary
//    visibility -- same handoff pattern as aggbf, verified R4/R8/R9).
//  - ballot sweep [verified R9]: per (m, 64-j-chunk) store one __ballot word;
//    scan+expand recomputes d2/w with textually identical expressions ->
//    identical edge set / bit-identical weights; order j-ascending.
//  - NEW: #pragma unroll 4 on the sweep j-loop (12 independent position loads
//    hoisted per iter) and on the phase-2 e-loop (4 emb loads in flight) --
//    latency pipelining only, no value changes.
__global__ __launch_bounds__(256) void k_agg(const float* __restrict__ pos,
                                             const int* __restrict__ types,
                                             const float* __restrict__ W1,
                                             const float* __restrict__ emb,
                                             unsigned short* __restrict__ W1bfT,
                                             unsigned short* __restrict__ aggbf,
                                             float* __restrict__ out) {
  __shared__ unsigned long long smask[TI][NATOMS / 64];  // 4 KB
  __shared__ float sw[TI][MAXE];
  __shared__ int   srow[TI][MAXE];
  __shared__ int   scnt[TI];
  const int tid = threadIdx.x;
  const int i0 = blockIdx.x * TI;

  // merged one-time prep (identical values to verified k_prep)
  if (blockIdx.x < 64) {
    int t = blockIdx.x * 256 + tid;         // 0..16383
    if (t == 0) out[0] = 0.0f;
    int n = t & 255;
    int kb = (t >> 8) * 4;                  // 0,4,..,252
#pragma unroll
    for (int i = 0; i < 4; ++i)
      W1bfT[n * HH + kb + i] = f2bf(W1[(kb + i) * HH + n]);  // read coalesced in n
  }

  float pix[TI], piy[TI], piz[TI];
#pragma unroll
  for (int m = 0; m < TI; ++m) {   // uniform addresses -> scalar loads
    pix[m] = 10.0f * pos[(i0 + m) * 3 + 0];
    piy[m] = 10.0f * pos[(i0 + m) * 3 + 1];
    piz[m] = 10.0f * pos[(i0 + m) * 3 + 2];
  }

  // sweep: lanes of a wave cover 64 consecutive j -> ballot bit r <-> j=64c+r
#pragma unroll 4
  for (int j = tid; j < NATOMS; j += 256) {
    float pjx = 10.0f * pos[j * 3 + 0];
    float pjy = 10.0f * pos[j * 3 + 1];
    float pjz = 10.0f * pos[j * 3 + 2];
    int c = j >> 6;                // wave-uniform chunk id
#pragma unroll
    for (int m = 0; m < TI; ++m) {
      float dx = pix[m] - pjx, dy = piy[m] - pjy, dz = piz[m] - pjz;
      float d2 = dx * dx;
      d2 = fmaf(dy, dy, d2);
      d2 = fmaf(dz, dz, d2);
      // ref mask: d2 > 1e-12 && sqrt(d2) <= 5  <=>  1e-12 < d2 <= 25 (fp32-exact)
      unsigned long long bal = __ballot(d2 > 1e-12f && d2 <= 25.0f);
      if ((tid & 63) == 0) smask[m][c] = bal;
    }
  }
  __syncthreads();

  // scan + expand: wave m handles atom m. Lane l owns chunks {2l, 2l+1}.
  {
    const int m = tid >> 6;        // 0..3 (4 waves)
    const int l = tid & 63;
    unsigned long long mA = smask[m][2 * l];
    unsigned long long mB = smask[m][2 * l + 1];
    int cA = __popcll(mA), cB = __popcll(mB);
    int s = cA + cB;
    int scan = s;                  // inclusive prefix over 64 lanes
#pragma unroll
    for (int off = 1; off < 64; off <<= 1) {
      int t = __shfl_up(scan, off);
      if (l >= off) scan += t;
    }
    int excl = scan - s;
    if (l == 63) scnt[m] = scan;   // per-atom total
    // same-source distance/weight recompute (bit-identical values)
    float px = 10.0f * pos[(i0 + m) * 3 + 0];
    float py = 10.0f * pos[(i0 + m) * 3 + 1];
    float pz = 10.0f * pos[(i0 + m) * 3 + 2];
#pragma unroll
    for (int h = 0; h < 2; ++h) {
      unsigned long long mask = h ? mB : mA;
      int base = h ? excl + cA : excl;
      int cbase = 64 * (2 * l + h);
      while (mask) {
        int r = __ffsll((long long)mask) - 1;
        mask &= mask - 1;
        int j = cbase + r;
        if (base < MAXE) {
          float pjx = 10.0f * pos[j * 3 + 0];
          float pjy = 10.0f * pos[j * 3 + 1];
          float pjz = 10.0f * pos[j * 3 + 2];
          float dx = px - pjx, dy = py - pjy, dz = pz - pjz;
          float d2 = dx * dx;
          d2 = fmaf(dy, dy, d2);
          d2 = fmaf(dz, dz, d2);
          float w = __expf(-sqrtf(d2));
          sw[m][base] = w;
          srow[m][base] = types[j] * DD;
        }
        ++base;
      }
    }
  }
  __syncthreads();

  // phase 2: 256 threads = 2 groups of 128 dims; group g -> atoms {g, g+2}.
  // unroll 4 -> 4 independent emb loads in flight; fma order preserved.
  const int d = tid & (DD - 1);
  const int g = tid >> 7;
#pragma unroll
  for (int mm = 0; mm < TI; mm += 2) {
    int m = g + mm;
    int nc = min(scnt[m], MAXE);
    float a = 0.0f;
#pragma unroll 4
    for (int e = 0; e < nc; ++e)
      a = fmaf(sw[m][e], emb[srow[m][e] + d], a);
    aggbf[(size_t)(i0 + m) * DD + d] = f2bf(a);   // feat is bf16 downstream anyway
  }
}

// MFMA MLP [verified, unchanged]: hidden = feat @ W1 (bf16 in, f32 acc), then
// sum(relu(hidden)*w2). 256 blocks x 512 threads (8 waves). Block stages
// feat[BM=32][256] bf16 in LDS (rows padded to 264 -> 2-way banks on b128
// reads). Wave w owns N-slice [32w,32w+32): 2Mx2N tiles x 8 K-steps of
// mfma_f32_16x16x32_bf16; B-frags straight from L2-resident W1bfT.
__global__ __launch_bounds__(512, 2) void k_mlp(const int* __restrict__ types,
                                                const float* __restrict__ emb,
                                                const unsigned short* __restrict__ aggbf,
                                                const unsigned short* __restrict__ W1bfT,
                                                const float* __restrict__ w2,
                                                float* __restrict__ out) {
  __shared__ unsigned short sA[BM][264];  // 16.5 KB
  __shared__ float sred[8];
  const int tid = threadIdx.x;
  const int n0 = blockIdx.x * BM;

  // stage feat = concat(emb[type], aggbf) as bf16: 32 rows x 64 chunks of 4
  for (int idx = tid; idx < BM * 64; idx += 512) {
    int row = idx >> 6;
    int cb = idx & 63;          // 4-col chunk
    int node = n0 + row;
    ushort4 u;
    if (cb < 32) {
      float4 v = *(const float4*)&emb[types[node] * DD + 4 * cb];
      u.x = f2bf(v.x); u.y = f2bf(v.y); u.z = f2bf(v.z); u.w = f2bf(v.w);
    } else {
      u = *(const ushort4*)&aggbf[(size_t)node * DD + 4 * (cb - 32)];
    }
    *(ushort4*)&sA[row][4 * cb] = u;
  }
  __syncthreads();

  const int lane = tid & 63;
  const int wv = tid >> 6;      // 0..7 -> N-slice
  const int nb = wv * 32;
  const int l15 = lane & 15;
  const int g = lane >> 4;      // 0..3 -> k-subgroup
  f32x4 acc00 = {}, acc01 = {}, acc10 = {}, acc11 = {};

  const unsigned short* bp0 = W1bfT + (nb + l15) * HH + 8 * g;
  const unsigned short* bp1 = bp0 + 16 * HH;
#pragma unroll
  for (int ks = 0; ks < 8; ++ks) {
    bf16x8 a0 = *(const bf16x8*)&sA[l15][ks * 32 + 8 * g];
    bf16x8 a1 = *(const bf16x8*)&sA[16 + l15][ks * 32 + 8 * g];
    bf16x8 b0 = *(const bf16x8*)(bp0 + ks * 32);
    bf16x8 b1 = *(const bf16x8*)(bp1 + ks * 32);
    acc00 = __builtin_amdgcn_mfma_f32_16x16x32_bf16(a0, b0, acc00, 0, 0, 0);
    acc01 = __builtin_amdgcn_mfma_f32_16x16x32_bf16(a0, b1, acc01, 0, 0, 0);
    acc10 = __builtin_amdgcn_mfma_f32_16x16x32_bf16(a1, b0, acc10, 0, 0, 0);
    acc11 = __builtin_amdgcn_mfma_f32_16x16x32_bf16(a1, b1, acc11, 0, 0, 0);
  }

  const float w2a = w2[nb + l15];
  const float w2b = w2[nb + 16 + l15];
  float p = 0.0f;
#pragma unroll
  for (int i = 0; i < 4; ++i) {
    p += fmaxf(acc00[i], 0.0f) * w2a;
    p += fmaxf(acc10[i], 0.0f) * w2a;
    p += fmaxf(acc01[i], 0.0f) * w2b;
    p += fmaxf(acc11[i], 0.0f) * w2b;
  }
#pragma unroll
  for (int off = 32; off; off >>= 1) p += __shfl_down(p, off);  // wave64 reduce
  if (lane == 0) sred[wv] = p;
  __syncthreads();
  if (tid == 0) {
    float t = 0.0f;
#pragma unroll
    for (int q = 0; q < 8; ++q) t += sred[q];
    atomicAdd(out, t * KJ2KCAL);
  }
}

extern "C" void kernel_launch(void* const* d_in, const int* in_sizes, int n_in,
                              void* d_out, int out_size, void* d_ws, size_t ws_size,
                              hipStream_t stream) {
  const float* pos = (const float*)d_in[0];
  const int*   typ = (const int*)d_in[1];
  const float* emb = (const float*)d_in[2];
  const float* W1  = (const float*)d_in[3];
  const float* w2  = (const float*)d_in[4];
  float* out = (float*)d_out;
  unsigned short* aggbf = (unsigned short*)d_ws;                        // 2 MB
  unsigned short* W1bfT = (unsigned short*)((char*)d_ws + (2u << 20));  // 128 KB

  hipLaunchKernelGGL(k_agg, dim3(NATOMS / TI), dim3(256), 0, stream,
                     pos, typ, W1, emb, W1bfT, aggbf, out);
  hipLaunchKernelGGL(k_mlp, dim3(NATOMS / BM), dim3(512), 0, stream,
                     typ, emb, aggbf, W1bfT, w2, out);
}